// Round 20
// baseline (113.934 us; speedup 1.0000x reference)
//
#include <hip/hip_runtime.h>

typedef __attribute__((ext_vector_type(8))) __bf16 bf16x8;
typedef __attribute__((ext_vector_type(4))) float f32x4;

#define M_ 256
#define N_ 4096
#define K_ 4096
#define SPLITK 4
#define KC (K_ / SPLITK)   // 1024
#define BM 128
#define BN 64
#define BK 32
#define KSTEPS (KC / BK)   // 32
#define NCH 20
#define LDSBUF 20480

// Tiled operand layout: 1KB bf16 tile = 16 rows x 32 k; tile(rt,kt) index
// rt*128+kt; slot lane = (row&15)+16*((k>>3)&3), elem = k&7.
// xgh/xgl: 16B/slot bf16 (async16-staged). z2: 2B/slot = 8x2-bit indices,
// decoded in-GEMM (LUT) to the same bf16 bits — verified R13.

// ---------- helpers ----------

__device__ __forceinline__ unsigned short f2bf(float f) {
  unsigned int u = __builtin_bit_cast(unsigned int, f);
  u += 0x7fffu + ((u >> 16) & 1u);
  return (unsigned short)(u >> 16);
}

__device__ __forceinline__ void async16(const void* g, void* l) {
  __builtin_amdgcn_global_load_lds(
      (const __attribute__((address_space(1))) unsigned int*)g,
      (__attribute__((address_space(3))) unsigned int*)l, 16, 0, 0);
}

__device__ __forceinline__ float lsq1(float y, float a, float s) {
  float yc = fminf(fmaxf(y, -a), a);
  return rintf(yc / s) * s;
}

// bf16 bit patterns for z_mod = idx-2: idx 0->-2, 1->-1, 2->0, 3->+1
#define ZLUT 0x3F800000BF80C000ull

// decode 8x2-bit word -> 16B (8 bf16), elem order ascending (verified R13)
__device__ __forceinline__ uint4 zdec(unsigned int w) {
  unsigned int d[4];
#pragma unroll
  for (int p = 0; p < 4; ++p) {
    const unsigned int lo = (unsigned int)((ZLUT >> (((w >> (4 * p)) & 3u) * 16)) & 0xFFFFull);
    const unsigned int hi = (unsigned int)((ZLUT >> (((w >> (4 * p + 2)) & 3u) * 16)) & 0xFFFFull);
    d[p] = lo | (hi << 16);
  }
  return make_uint4(d[0], d[1], d[2], d[3]);
}

// ---------- K1: fused producer (verified R13 — DO NOT TOUCH) ----------
// blocks [0, NQB): lattice-quantize W -> z2 (2-bit indices, tiled slot order).
//   z dot: f32 UNFUSED mul+add, sequential ascending, contract(off) — matches
//   XLA:CPU's fmul/fadd chain (contraction was the R1/R9/R10 0.701 bug).
// blocks [NQB, NQB+NXB): xg = x_blocks @ G^T -> bf16 hi/lo (tiled layout).

#define NQB ((N_ * K_ / 8) / 256)  // 8192
#define NXB ((M_ * K_ / 8) / 256)  // 512

__global__ __launch_bounds__(256) void k_prep(const float* __restrict__ W,
                                              const float* __restrict__ theta,
                                              const float* __restrict__ Ginv,
                                              const float* __restrict__ x,
                                              const float* __restrict__ G,
                                              unsigned short* __restrict__ z2,
                                              unsigned short* __restrict__ hi,
                                              unsigned short* __restrict__ lo,
                                              int kTheta) {
  __shared__ float Ms[64];
  const int tid = threadIdx.x;
  const bool isQ = blockIdx.x < NQB;
  if (tid < 64) Ms[tid] = isQ ? Ginv[tid] : G[tid];
  __syncthreads();

  if (isQ) {
#pragma clang fp contract(off)
    const int s = blockIdx.x * 256 + tid;       // output slot
    const int lane6 = s & 63;
    const int tile = s >> 6;
    const int o  = ((tile >> 7) << 4) + (lane6 & 15);   // W row
    const int kb = ((tile & 127) << 2) + (lane6 >> 4);  // 8-elt k-block
    const float4* wp = (const float4*)(W + ((size_t)o << 12) + ((size_t)kb << 3));
    const float4 w0 = wp[0], w1 = wp[1];
    float sc = 0.f;
    for (int t = 0; t < kTheta; ++t) sc += theta[o * kTheta + t];
    sc /= (float)kTheta;
    const float wsv[8] = {w0.x * sc, w0.y * sc, w0.z * sc, w0.w * sc,
                          w1.x * sc, w1.y * sc, w1.z * sc, w1.w * sc};
    unsigned int word = 0u;
#pragma unroll
    for (int i = 0; i < 8; ++i) {
      float t = 0.f;
#pragma unroll
      for (int j = 0; j < 8; ++j)
        t = t + wsv[j] * Ms[j * 8 + i];   // contract(off): separate rn mul + rn add
      const int zi = (int)rintf(t);
      word |= (unsigned int)((zi + 2) & 3) << (2 * i);
    }
    z2[s] = (unsigned short)word;
  } else {
    const int s = (blockIdx.x - NQB) * 256 + tid;
    const int lane6 = s & 63;
    const int tile = s >> 6;
    const int m  = ((tile >> 7) << 4) + (lane6 & 15);
    const int kb = ((tile & 127) << 2) + (lane6 >> 4);
    const float4* xp = (const float4*)(x + ((size_t)m << 12) + ((size_t)kb << 3));
    const float4 a0 = xp[0], a1 = xp[1];
    float xv[8] = {a0.x, a0.y, a0.z, a0.w, a1.x, a1.y, a1.z, a1.w};
    unsigned int ph[4] = {0u, 0u, 0u, 0u}, pl[4] = {0u, 0u, 0u, 0u};
#pragma unroll
    for (int i = 0; i < 8; ++i) {
      float t = 0.f;
#pragma unroll
      for (int j = 0; j < 8; ++j) t = fmaf(xv[j], Ms[i * 8 + j], t);
      const unsigned short hb = f2bf(t);
      const float hf = __builtin_bit_cast(float, (unsigned int)hb << 16);
      const unsigned short lb = f2bf(t - hf);
      ph[i >> 1] |= ((unsigned int)hb) << ((i & 1) * 16);
      pl[i >> 1] |= ((unsigned int)lb) << ((i & 1) * 16);
    }
    *(uint4*)(hi + ((size_t)s << 3)) = make_uint4(ph[0], ph[1], ph[2], ph[3]);
    *(uint4*)(lo + ((size_t)s << 3)) = make_uint4(pl[0], pl[1], pl[2], pl[3]);
  }
}

// ---------- K2: split-K GEMM (R13 loop verbatim) + last-block fused epilogue ----------
// 512 thr = 8 waves (4m x 2n), tile 128x64, BK=32, 2-barrier double buffer.
// A: async16 contiguous-1KB; wave w stages A_hi tile w + A_lo tile w.
// B: waves 0-3 load z2 word (pipelined 1 step ahead), zdec, ds_write_b128.
// Per-accumulator MFMA k-order (ascending k32, hi-then-lo) = verified r3-r19.
// EPILOGUE FUSION: after the C-write, threadfence + per-(mt,nt) atomic counter;
// the 4th-arriving sk-block re-reads the 4 partials and applies
// ((p0+p1)+p2)+p3 + bias + LSQ — EXACTLY the verified k_epi order.
// No spin, no co-residency assumption; device-scope fence+atomic (G16).

__global__ __launch_bounds__(512, 2) void k_gemm(const unsigned short* __restrict__ xgh,
                                                 const unsigned short* __restrict__ xgl,
                                                 const unsigned short* __restrict__ z2,
                                                 float* __restrict__ part,
                                                 unsigned int* __restrict__ cnt,
                                                 const float* __restrict__ bias,
                                                 const float* __restrict__ alpha,
                                                 float* __restrict__ out) {
  __shared__ uint4 smem4[2 * LDSBUF / 16];  // 40KB double buffer
  char* smem = (char*)smem4;

  const int tid = threadIdx.x;
  const int lane = tid & 63, wave = tid >> 6;
  const int wr = wave >> 1, wc = wave & 1;   // wave grid 4m x 2n
  const int b = blockIdx.x;
  const int mt = b & 1;
  const int sk = (b >> 1) & 3;
  const int nt = b >> 3;                     // 0..63
  const int k0t = sk * (KC / 32);
  const int rowa16 = mt * (BM / 16);
  const int rowb16 = nt * (BN / 16);
  const int lrow = lane & 15, lkg = lane >> 4;

  // A chunks: ci=0 -> A_hi tile `wave` (chunk wave); ci=1 -> A_lo tile `wave` (chunk wave+8)
  const unsigned short* asrc[2];
  int aldo[2];
#pragma unroll
  for (int ci = 0; ci < 2; ++ci) {
    const unsigned short* P = (ci == 0) ? xgh : xgl;
    asrc[ci] = P + (((size_t)((rowa16 + wave) * 128 + k0t)) << 9) + lane * 8;
    aldo[ci] = (ci * 8 + wave) * 1024;
  }
  // B role (waves 0-3): B tile rowb16+wave -> chunk 16+wave
  const bool brole = (wave < 4);
  const unsigned short* zsrc = nullptr;
  int bofs = 0;
  if (brole) {
    zsrc = z2 + (((size_t)((rowb16 + wave) * 128 + k0t)) << 6) + lane;
    bofs = (16 + wave) * 1024 + lane * 16;
  }

  f32x4 acc[2][2] = {};

  // prologue: stage step 0 into buffer 0; preload zw for step 1
  unsigned int zw = 0;
#pragma unroll
  for (int ci = 0; ci < 2; ++ci) async16(asrc[ci], smem + aldo[ci]);
  if (brole) {
    zw = zsrc[0];
    *(uint4*)(smem + bofs) = zdec(zw);
    zw = zsrc[64];  // step 1 word
  }
  __syncthreads();

  for (int ks = 0; ks < KSTEPS; ++ks) {
    const int cur = (ks & 1) * LDSBUF;
    const int nxt = LDSBUF - cur;
    if (ks + 1 < KSTEPS) {
#pragma unroll
      for (int ci = 0; ci < 2; ++ci)
        async16(asrc[ci] + (size_t)(ks + 1) * 512, smem + nxt + aldo[ci]);
      if (brole) {
        *(uint4*)(smem + nxt + bofs) = zdec(zw);
        if (ks + 2 < KSTEPS) zw = zsrc[(size_t)(ks + 2) * 64];
      }
    }

    bf16x8 bfr[2], ah[2], al[2];
#pragma unroll
    for (int nf = 0; nf < 2; ++nf)
      bfr[nf] = *(const bf16x8*)(smem + cur + (16 + wc * 2 + nf) * 1024 + lane * 16);
#pragma unroll
    for (int mf = 0; mf < 2; ++mf) {
      ah[mf] = *(const bf16x8*)(smem + cur + (wr * 2 + mf) * 1024 + lane * 16);
      al[mf] = *(const bf16x8*)(smem + cur + (8 + wr * 2 + mf) * 1024 + lane * 16);
    }
#pragma unroll
    for (int mf = 0; mf < 2; ++mf)
#pragma unroll
      for (int nf = 0; nf < 2; ++nf) {
        acc[mf][nf] = __builtin_amdgcn_mfma_f32_16x16x32_bf16(ah[mf], bfr[nf], acc[mf][nf], 0, 0, 0);
        acc[mf][nf] = __builtin_amdgcn_mfma_f32_16x16x32_bf16(al[mf], bfr[nf], acc[mf][nf], 0, 0, 0);
      }
    __syncthreads();  // drains vmcnt+lgkm: stage above targets NEXT buffer
  }

  // C/D layout (m89-verified): col = lane&15, row = (lane>>4)*4 + reg
  float* pb = part + (size_t)sk * (M_ * N_);
  const int row_a = mt * BM, row_b = nt * BN;
#pragma unroll
  for (int mf = 0; mf < 2; ++mf)
#pragma unroll
    for (int nf = 0; nf < 2; ++nf)
#pragma unroll
      for (int r = 0; r < 4; ++r) {
        const int m = row_a + wr * 32 + mf * 16 + lkg * 4 + r;
        const int n = row_b + wc * 32 + nf * 16 + lrow;
        pb[(size_t)m * N_ + n] = acc[mf][nf][r];
      }

  // ---- last-arriving-block fused epilogue ----
  __syncthreads();                 // all waves' partial stores issued
  __shared__ unsigned int s_old;
  if (tid == 0) {
    __threadfence();               // publish this block's partial (device scope)
    s_old = atomicAdd(&cnt[mt * 64 + nt], 1u);
  }
  __syncthreads();
  if (s_old != 3u) return;         // not the 4th block for this tile
  __threadfence();                 // acquire: other blocks' partials visible

  const float a = fmaxf(alpha[0], 0.f) + 1e-8f;
  const float s = a / 127.0f;
  // tile = rows mt*128..+128, cols nt*64..+64 -> 2048 float4 groups
#pragma unroll
  for (int it = 0; it < 4; ++it) {
    const int e = it * 512 + tid;            // 0..2047
    const int row = e >> 4;                  // 0..127
    const int c4 = e & 15;                   // 0..15
    const size_t off = (size_t)(mt * BM + row) * N_ + nt * BN + c4 * 4;
    const float4 p0 = *(const float4*)(part + off);
    const float4 p1 = *(const float4*)(part + (size_t)1 * M_ * N_ + off);
    const float4 p2 = *(const float4*)(part + (size_t)2 * M_ * N_ + off);
    const float4 p3 = *(const float4*)(part + (size_t)3 * M_ * N_ + off);
    const float4 bv = *(const float4*)(bias + nt * BN + c4 * 4);
    float4 o;
    o.x = lsq1(((p0.x + p1.x) + p2.x) + p3.x + bv.x, a, s);
    o.y = lsq1(((p0.y + p1.y) + p2.y) + p3.y + bv.y, a, s);
    o.z = lsq1(((p0.z + p1.z) + p2.z) + p3.z + bv.z, a, s);
    o.w = lsq1(((p0.w + p1.w) + p2.w) + p3.w + bv.w, a, s);
    *(float4*)(out + off) = o;
  }
}

// ---------- launch ----------

extern "C" void kernel_launch(void* const* d_in, const int* in_sizes, int n_in,
                              void* d_out, int out_size, void* d_ws, size_t ws_size,
                              hipStream_t stream) {
  const float* x     = (const float*)d_in[0];
  const float* W     = (const float*)d_in[1];
  const float* bias  = (const float*)d_in[2];
  const float* theta = (const float*)d_in[3];
  const float* alpha = (const float*)d_in[4];
  const float* G     = (const float*)d_in[5];
  const float* Ginv  = (const float*)d_in[6];
  float* out = (float*)d_out;

  const int O = in_sizes[2];           // 4096
  const int kTheta = in_sizes[3] / O;  // 1

  // ws layout: xg_hi 2MB | xg_lo 2MB | z2 4MB | part [4][M][N] 16MB | cnt 512B
  char* ws = (char*)d_ws;
  unsigned short* xgh = (unsigned short*)ws;
  unsigned short* xgl = (unsigned short*)(ws + 2097152);
  unsigned short* z2  = (unsigned short*)(ws + 4194304);
  float* part = (float*)(ws + 8388608);
  unsigned int* cnt = (unsigned int*)(ws + 25165824);
  if (ws_size < 25166848) return;  // guard: need 24MB + counters

  hipMemsetAsync(cnt, 0, 128 * sizeof(unsigned int), stream);  // ws poisoned 0xAA; zero per call
  k_prep<<<NQB + NXB, 256, 0, stream>>>(W, theta, Ginv, x, G, z2, xgh, xgl, kTheta);
  k_gemm<<<2 * SPLITK * 64, 512, 0, stream>>>(xgh, xgl, z2, part, cnt, bias, alpha, out);
}

// Round 21
// 49.062 us; speedup vs baseline: 2.3223x; 2.3223x over previous
//
#include <hip/hip_runtime.h>

typedef __attribute__((ext_vector_type(8))) __bf16 bf16x8;
typedef __attribute__((ext_vector_type(4))) float f32x4;

#define M_ 256
#define N_ 4096
#define K_ 4096
#define SPLITK 4
#define KC (K_ / SPLITK)   // 1024
#define BM 128
#define BN 64
#define BK 32
#define KSTEPS (KC / BK)   // 32
#define NCH 20
#define LDSBUF 20480

// Tiled operand layout: 1KB bf16 tile = 16 rows x 32 k; tile(rt,kt) index
// rt*128+kt; slot lane = (row&15)+16*((k>>3)&3), elem = k&7.
// xgh/xgl: 16B/slot bf16 (async16-staged). z2: 2B/slot = 8x2-bit indices,
// decoded in-GEMM (LUT) to the same bf16 bits — verified R13.

// ---------- helpers ----------

__device__ __forceinline__ unsigned short f2bf(float f) {
  unsigned int u = __builtin_bit_cast(unsigned int, f);
  u += 0x7fffu + ((u >> 16) & 1u);
  return (unsigned short)(u >> 16);
}

__device__ __forceinline__ void async16(const void* g, void* l) {
  __builtin_amdgcn_global_load_lds(
      (const __attribute__((address_space(1))) unsigned int*)g,
      (__attribute__((address_space(3))) unsigned int*)l, 16, 0, 0);
}

__device__ __forceinline__ float lsq1(float y, float a, float s) {
  float yc = fminf(fmaxf(y, -a), a);
  return rintf(yc / s) * s;
}

// bf16 bit patterns for z_mod = idx-2: idx 0->-2, 1->-1, 2->0, 3->+1
#define ZLUT 0x3F800000BF80C000ull

// decode 8x2-bit word -> 16B (8 bf16), elem order ascending (verified R13)
__device__ __forceinline__ uint4 zdec(unsigned int w) {
  unsigned int d[4];
#pragma unroll
  for (int p = 0; p < 4; ++p) {
    const unsigned int lo = (unsigned int)((ZLUT >> (((w >> (4 * p)) & 3u) * 16)) & 0xFFFFull);
    const unsigned int hi = (unsigned int)((ZLUT >> (((w >> (4 * p + 2)) & 3u) * 16)) & 0xFFFFull);
    d[p] = lo | (hi << 16);
  }
  return make_uint4(d[0], d[1], d[2], d[3]);
}

// ---------- K1: fused producer (verified R13 — DO NOT TOUCH) ----------
// blocks [0, NQB): lattice-quantize W -> z2 (2-bit indices, tiled slot order).
//   z dot: f32 UNFUSED mul+add, sequential ascending, contract(off) — matches
//   XLA:CPU's fmul/fadd chain (contraction was the R1/R9/R10 0.701 bug).
// blocks [NQB, NQB+NXB): xg = x_blocks @ G^T -> bf16 hi/lo (tiled layout).

#define NQB ((N_ * K_ / 8) / 256)  // 8192
#define NXB ((M_ * K_ / 8) / 256)  // 512

__global__ __launch_bounds__(256) void k_prep(const float* __restrict__ W,
                                              const float* __restrict__ theta,
                                              const float* __restrict__ Ginv,
                                              const float* __restrict__ x,
                                              const float* __restrict__ G,
                                              unsigned short* __restrict__ z2,
                                              unsigned short* __restrict__ hi,
                                              unsigned short* __restrict__ lo,
                                              int kTheta) {
  __shared__ float Ms[64];
  const int tid = threadIdx.x;
  const bool isQ = blockIdx.x < NQB;
  if (tid < 64) Ms[tid] = isQ ? Ginv[tid] : G[tid];
  __syncthreads();

  if (isQ) {
#pragma clang fp contract(off)
    const int s = blockIdx.x * 256 + tid;       // output slot
    const int lane6 = s & 63;
    const int tile = s >> 6;
    const int o  = ((tile >> 7) << 4) + (lane6 & 15);   // W row
    const int kb = ((tile & 127) << 2) + (lane6 >> 4);  // 8-elt k-block
    const float4* wp = (const float4*)(W + ((size_t)o << 12) + ((size_t)kb << 3));
    const float4 w0 = wp[0], w1 = wp[1];
    float sc = 0.f;
    for (int t = 0; t < kTheta; ++t) sc += theta[o * kTheta + t];
    sc /= (float)kTheta;
    const float wsv[8] = {w0.x * sc, w0.y * sc, w0.z * sc, w0.w * sc,
                          w1.x * sc, w1.y * sc, w1.z * sc, w1.w * sc};
    unsigned int word = 0u;
#pragma unroll
    for (int i = 0; i < 8; ++i) {
      float t = 0.f;
#pragma unroll
      for (int j = 0; j < 8; ++j)
        t = t + wsv[j] * Ms[j * 8 + i];   // contract(off): separate rn mul + rn add
      const int zi = (int)rintf(t);
      word |= (unsigned int)((zi + 2) & 3) << (2 * i);
    }
    z2[s] = (unsigned short)word;
  } else {
    const int s = (blockIdx.x - NQB) * 256 + tid;
    const int lane6 = s & 63;
    const int tile = s >> 6;
    const int m  = ((tile >> 7) << 4) + (lane6 & 15);
    const int kb = ((tile & 127) << 2) + (lane6 >> 4);
    const float4* xp = (const float4*)(x + ((size_t)m << 12) + ((size_t)kb << 3));
    const float4 a0 = xp[0], a1 = xp[1];
    float xv[8] = {a0.x, a0.y, a0.z, a0.w, a1.x, a1.y, a1.z, a1.w};
    unsigned int ph[4] = {0u, 0u, 0u, 0u}, pl[4] = {0u, 0u, 0u, 0u};
#pragma unroll
    for (int i = 0; i < 8; ++i) {
      float t = 0.f;
#pragma unroll
      for (int j = 0; j < 8; ++j) t = fmaf(xv[j], Ms[i * 8 + j], t);
      const unsigned short hb = f2bf(t);
      const float hf = __builtin_bit_cast(float, (unsigned int)hb << 16);
      const unsigned short lb = f2bf(t - hf);
      ph[i >> 1] |= ((unsigned int)hb) << ((i & 1) * 16);
      pl[i >> 1] |= ((unsigned int)lb) << ((i & 1) * 16);
    }
    *(uint4*)(hi + ((size_t)s << 3)) = make_uint4(ph[0], ph[1], ph[2], ph[3]);
    *(uint4*)(lo + ((size_t)s << 3)) = make_uint4(pl[0], pl[1], pl[2], pl[3]);
  }
}

// ---------- K2: split-K GEMM (R13 verbatim — the verified best) ----------
// 512 thr = 8 waves (4m x 2n), tile 128x64, BK=32, 2-barrier double buffer.
// A: async16 contiguous-1KB; wave w stages A_hi tile w + A_lo tile w.
// B: waves 0-3 load z2 word (pipelined 1 step ahead), zdec, ds_write_b128
//    into chunk 16+wave. Per-accumulator MFMA k-order (ascending k32,
//    hi-then-lo) = verified r3-r20. NO device-scope fences in-kernel (R20
//    lesson: threadfence poisons the L2-resident operand reuse, 4x slowdown).

__global__ __launch_bounds__(512, 4) void k_gemm(const unsigned short* __restrict__ xgh,
                                                 const unsigned short* __restrict__ xgl,
                                                 const unsigned short* __restrict__ z2,
                                                 float* __restrict__ part) {
  __shared__ uint4 smem4[2 * LDSBUF / 16];  // 40KB double buffer
  char* smem = (char*)smem4;

  const int tid = threadIdx.x;
  const int lane = tid & 63, wave = tid >> 6;
  const int wr = wave >> 1, wc = wave & 1;   // wave grid 4m x 2n
  const int b = blockIdx.x;
  const int mt = b & 1;
  const int sk = (b >> 1) & 3;
  const int nt = b >> 3;                     // 0..63
  const int k0t = sk * (KC / 32);
  const int rowa16 = mt * (BM / 16);
  const int rowb16 = nt * (BN / 16);
  const int lrow = lane & 15, lkg = lane >> 4;

  // A chunks: ci=0 -> A_hi tile `wave` (chunk wave); ci=1 -> A_lo tile `wave` (chunk wave+8)
  const unsigned short* asrc[2];
  int aldo[2];
#pragma unroll
  for (int ci = 0; ci < 2; ++ci) {
    const unsigned short* P = (ci == 0) ? xgh : xgl;
    asrc[ci] = P + (((size_t)((rowa16 + wave) * 128 + k0t)) << 9) + lane * 8;
    aldo[ci] = (ci * 8 + wave) * 1024;
  }
  // B role (waves 0-3): B tile rowb16+wave -> chunk 16+wave
  const bool brole = (wave < 4);
  const unsigned short* zsrc = nullptr;
  int bofs = 0;
  if (brole) {
    zsrc = z2 + (((size_t)((rowb16 + wave) * 128 + k0t)) << 6) + lane;
    bofs = (16 + wave) * 1024 + lane * 16;
  }

  f32x4 acc[2][2] = {};

  // prologue: stage step 0 into buffer 0; preload zw for step 1
  unsigned int zw = 0;
#pragma unroll
  for (int ci = 0; ci < 2; ++ci) async16(asrc[ci], smem + aldo[ci]);
  if (brole) {
    zw = zsrc[0];
    *(uint4*)(smem + bofs) = zdec(zw);
    zw = zsrc[64];  // step 1 word
  }
  __syncthreads();

  for (int ks = 0; ks < KSTEPS; ++ks) {
    const int cur = (ks & 1) * LDSBUF;
    const int nxt = LDSBUF - cur;
    if (ks + 1 < KSTEPS) {
#pragma unroll
      for (int ci = 0; ci < 2; ++ci)
        async16(asrc[ci] + (size_t)(ks + 1) * 512, smem + nxt + aldo[ci]);
      if (brole) {
        *(uint4*)(smem + nxt + bofs) = zdec(zw);
        if (ks + 2 < KSTEPS) zw = zsrc[(size_t)(ks + 2) * 64];
      }
    }

    bf16x8 bfr[2], ah[2], al[2];
#pragma unroll
    for (int nf = 0; nf < 2; ++nf)
      bfr[nf] = *(const bf16x8*)(smem + cur + (16 + wc * 2 + nf) * 1024 + lane * 16);
#pragma unroll
    for (int mf = 0; mf < 2; ++mf) {
      ah[mf] = *(const bf16x8*)(smem + cur + (wr * 2 + mf) * 1024 + lane * 16);
      al[mf] = *(const bf16x8*)(smem + cur + (8 + wr * 2 + mf) * 1024 + lane * 16);
    }
#pragma unroll
    for (int mf = 0; mf < 2; ++mf)
#pragma unroll
      for (int nf = 0; nf < 2; ++nf) {
        acc[mf][nf] = __builtin_amdgcn_mfma_f32_16x16x32_bf16(ah[mf], bfr[nf], acc[mf][nf], 0, 0, 0);
        acc[mf][nf] = __builtin_amdgcn_mfma_f32_16x16x32_bf16(al[mf], bfr[nf], acc[mf][nf], 0, 0, 0);
      }
    __syncthreads();  // drains vmcnt+lgkm: stage above targets NEXT buffer
  }

  // C/D layout (m89-verified): col = lane&15, row = (lane>>4)*4 + reg
  float* pb = part + (size_t)sk * (M_ * N_);
  const int row_a = mt * BM, row_b = nt * BN;
#pragma unroll
  for (int mf = 0; mf < 2; ++mf)
#pragma unroll
    for (int nf = 0; nf < 2; ++nf)
#pragma unroll
      for (int r = 0; r < 4; ++r) {
        const int m = row_a + wr * 32 + mf * 16 + lkg * 4 + r;
        const int n = row_b + wc * 32 + nf * 16 + lrow;
        pb[(size_t)m * N_ + n] = acc[mf][nf][r];
      }
}

// ---------- K3: reduce 4 split-K partials + bias + LSQ epilogue (verified) ----------

__global__ __launch_bounds__(256) void k_epi(const float* __restrict__ part,
                                             const float* __restrict__ bias,
                                             const float* __restrict__ alpha,
                                             float* __restrict__ out) {
  const int i4 = blockIdx.x * 256 + threadIdx.x;  // over M_*N_/4
  const size_t off = (size_t)i4 * 4;
  const float4 p0 = *(const float4*)(part + off);
  const float4 p1 = *(const float4*)(part + (size_t)1 * M_ * N_ + off);
  const float4 p2 = *(const float4*)(part + (size_t)2 * M_ * N_ + off);
  const float4 p3 = *(const float4*)(part + (size_t)3 * M_ * N_ + off);
  const int n = (int)(off & (N_ - 1));
  const float4 bv = *(const float4*)(bias + n);
  const float a = fmaxf(alpha[0], 0.f) + 1e-8f;
  const float s = a / 127.0f;
  float4 o;
  o.x = lsq1(((p0.x + p1.x) + p2.x) + p3.x + bv.x, a, s);
  o.y = lsq1(((p0.y + p1.y) + p2.y) + p3.y + bv.y, a, s);
  o.z = lsq1(((p0.z + p1.z) + p2.z) + p3.z + bv.z, a, s);
  o.w = lsq1(((p0.w + p1.w) + p2.w) + p3.w + bv.w, a, s);
  *(float4*)(out + off) = o;
}

// ---------- launch ----------

extern "C" void kernel_launch(void* const* d_in, const int* in_sizes, int n_in,
                              void* d_out, int out_size, void* d_ws, size_t ws_size,
                              hipStream_t stream) {
  const float* x     = (const float*)d_in[0];
  const float* W     = (const float*)d_in[1];
  const float* bias  = (const float*)d_in[2];
  const float* theta = (const float*)d_in[3];
  const float* alpha = (const float*)d_in[4];
  const float* G     = (const float*)d_in[5];
  const float* Ginv  = (const float*)d_in[6];
  float* out = (float*)d_out;

  const int O = in_sizes[2];           // 4096
  const int kTheta = in_sizes[3] / O;  // 1

  // ws layout: xg_hi 2MB | xg_lo 2MB | z2 4MB | partials [4][M][N] 16MB
  char* ws = (char*)d_ws;
  unsigned short* xgh = (unsigned short*)ws;
  unsigned short* xgl = (unsigned short*)(ws + 2097152);
  unsigned short* z2  = (unsigned short*)(ws + 4194304);
  float* part = (float*)(ws + 8388608);
  if (ws_size < 25165824) return;  // guard: need 24MB scratch

  k_prep<<<NQB + NXB, 256, 0, stream>>>(W, theta, Ginv, x, G, z2, xgh, xgl, kTheta);
  k_gemm<<<2 * SPLITK * 64, 512, 0, stream>>>(xgh, xgl, z2, part);
  k_epi<<<(M_ * N_ / 4) / 256, 256, 0, stream>>>(part, bias, alpha, out);
}